// Round 8
// baseline (375.603 us; speedup 1.0000x reference)
//
#include <hip/hip_runtime.h>
#include <hip/hip_bf16.h>
#include <math.h>

#define W_WORDS  4096
#define T_TOKENS 32768
#define N_EMBD   512
#define N_HIDDEN 2048
#define CAP      64      // max words per token (Binomial(4096,0.004): mean 16.4)
#define SCAN_SUB_A 14400 // 16KB sub-chunks scanned in mega1 (of 32768); rest in mega2

typedef __attribute__((ext_vector_type(8))) short bf16x8;   // MFMA A/B frag (4 VGPR)
typedef __attribute__((ext_vector_type(4))) float f32x4;    // MFMA C/D frag
typedef __attribute__((ext_vector_type(4))) int   i32x4;
typedef unsigned int u32;

#define GLOBAL_AS __attribute__((address_space(1)))
#define LDS_AS    __attribute__((address_space(3)))

// ---------------------------------------------------------------------------
// Mask-scan work item: one sub-chunk = 4096 int32 (16 KB), nt loads.
// ---------------------------------------------------------------------------
__device__ inline void scan_mask_block(const int* __restrict__ mask,
                                       int* __restrict__ counts,
                                       unsigned short* __restrict__ lists,
                                       int sub)
{
    const size_t base = (size_t)sub * 4096;
#pragma unroll
    for (int k = 0; k < 4; ++k) {
        const size_t e = base + (size_t)k * 1024 + (size_t)threadIdx.x * 4;
        const i32x4 v = __builtin_nontemporal_load((const i32x4*)(mask + e));
        if ((v.x | v.y | v.z | v.w) == 0) continue;
        const int w  = (int)(e >> 15);
        const int t0 = (int)(e & (T_TOKENS - 1));
        if (v.x) { const int p = atomicAdd(&counts[t0+0], 1); if (p < CAP) lists[(size_t)(t0+0)*CAP+p] = (unsigned short)w; }
        if (v.y) { const int p = atomicAdd(&counts[t0+1], 1); if (p < CAP) lists[(size_t)(t0+1)*CAP+p] = (unsigned short)w; }
        if (v.z) { const int p = atomicAdd(&counts[t0+2], 1); if (p < CAP) lists[(size_t)(t0+2)*CAP+p] = (unsigned short)w; }
        if (v.w) { const int p = atomicAdd(&counts[t0+3], 1); if (p < CAP) lists[(size_t)(t0+3)*CAP+p] = (unsigned short)w; }
    }
}

// ---------------------------------------------------------------------------
// Prep kernel: convert in_words->bf16, transpose W_fc / W_proj,
// zero counts + steal counters.
//   blocks [0,1024)     : convert words
//   blocks [1024,2048)  : transpose W_fc
//   blocks [2048,3072)  : transpose W_proj
//   blocks [3072,3105)  : zero counts region (33792 ints >= 32768+2 ctrs)
// ---------------------------------------------------------------------------
__global__ __launch_bounds__(256) void prep_kernel(
    const float* __restrict__ in_words, __hip_bfloat16* __restrict__ words_bf,
    const float* __restrict__ W_fc,     __hip_bfloat16* __restrict__ WfcT,
    const float* __restrict__ W_proj,   __hip_bfloat16* __restrict__ WprojT,
    int* __restrict__ counts)
{
    __shared__ float tile[32][33];
    const int b = blockIdx.x;

    if (b < 1024) {
        const size_t gid = (size_t)b * 256 + threadIdx.x;
        const float4 a0 = ((const float4*)in_words)[2 * gid];
        const float4 a1 = ((const float4*)in_words)[2 * gid + 1];
        union { __hip_bfloat16 t[8]; bf16x8 v; } u;
        u.t[0] = __float2bfloat16(a0.x); u.t[1] = __float2bfloat16(a0.y);
        u.t[2] = __float2bfloat16(a0.z); u.t[3] = __float2bfloat16(a0.w);
        u.t[4] = __float2bfloat16(a1.x); u.t[5] = __float2bfloat16(a1.y);
        u.t[6] = __float2bfloat16(a1.z); u.t[7] = __float2bfloat16(a1.w);
        *(bf16x8*)(words_bf + 8 * gid) = u.v;
        return;
    }
    if (b < 3072) {
        const float* in;  __hip_bfloat16* out; int R, C, bx, by;
        if (b < 2048) { in = W_fc;   out = WfcT;   R = N_EMBD;   C = N_HIDDEN;
                        const int l = b - 1024; bx = l & 63; by = l >> 6; }
        else          { in = W_proj; out = WprojT; R = N_HIDDEN; C = N_EMBD;
                        const int l = b - 2048; bx = l & 15; by = l >> 4; }
        const int tx = threadIdx.x & 31, ty = threadIdx.x >> 5;
        const int r0 = by * 32, c0 = bx * 32;
#pragma unroll
        for (int i = 0; i < 4; ++i) {
            const int r = ty + i * 8;
            tile[r][tx] = in[(size_t)(r0 + r) * C + c0 + tx];
        }
        __syncthreads();
#pragma unroll
        for (int i = 0; i < 4; ++i) {
            const int r = ty + i * 8;
            out[(size_t)(c0 + r) * R + r0 + tx] = __float2bfloat16(tile[tx][r]);
        }
        return;
    }
    const int idx = (b - 3072) * 1024 + (int)threadIdx.x * 4;
    *(i32x4*)(counts + idx) = (i32x4){0, 0, 0, 0};
}

// ---------------------------------------------------------------------------
// Work-stealing mega kernel: steal index i from global counter.
//   i < nTiles                -> GEMM tile i
//   nTiles <= i < nTiles+nBig -> scan big-chunk (4 x 16 KB sub-chunks)
// GEMM: C[M,N] = A[M,K] @ BT[N,K]^T. BK=32, 4 waves (2x2), 16x16x32 MFMA,
// global_load_lds width-16 staging (inner code identical to R6).
// MODE 0: C = bf16(gelu_exact(acc))
// MODE 1: Cf32 = acc + Res, AND Cbf = bf16(acc + Res)
// ---------------------------------------------------------------------------
template <int BM, int BN, int MODE>
__global__ __launch_bounds__(256) void mega_kernel(
    const __hip_bfloat16* __restrict__ A,
    const __hip_bfloat16* __restrict__ BT,
    const float* __restrict__ Res,
    void* __restrict__ Cout,
    __hip_bfloat16* __restrict__ Cbf,
    int M, int N, int K, int nTiles, int gridX,
    const int* __restrict__ mask, int* __restrict__ counts,
    unsigned short* __restrict__ lists, int scanSubBase, int nBig,
    int* __restrict__ ctr)
{
    constexpr int BK = 32;
    constexpr int WM = BM / 2, WN = BN / 2;
    constexpr int FM = WM / 16, FN = WN / 16;
    constexpr int NA = (BM * 64) / 4096;
    constexpr int NB = (BN * 64) / 4096;

    __shared__ __align__(16) char smem[(BM + BN) * 64];
    __shared__ int s_idx;
    char* As = smem;
    char* Bs = smem + BM * 64;

    const int tid  = threadIdx.x;
    const int lane = tid & 63;
    const int wid  = tid >> 6;
    const int wm   = wid >> 1, wn = wid & 1;

    for (;;) {
        __syncthreads();                       // protect s_idx from prev readers
        if (tid == 0) s_idx = atomicAdd(ctr, 1);
        __syncthreads();
        const int i = s_idx;
        if (i >= nTiles + nBig) return;

        if (i >= nTiles) {                     // ---- scan role ----
            const int big = i - nTiles;
#pragma unroll
            for (int j = 0; j < 4; ++j)
                scan_mask_block(mask, counts, lists, scanSubBase + big * 4 + j);
            continue;
        }

        // ---- GEMM tile i ----
        const int bm = (i / gridX) * BM;
        const int bn = (i % gridX) * BN;

        f32x4 acc[FM][FN] = {};

        for (int k0 = 0; k0 < K; k0 += BK) {
#pragma unroll
            for (int a = 0; a < NA; ++a) {
                const int c    = a * 4 + wid;
                const int loff = c * 1024 + lane * 16;
                const int row  = loff >> 6;
                const int kb   = loff & 63;
                const __hip_bfloat16* src = A + (size_t)(bm + row) * K + k0 + (kb >> 1);
                __builtin_amdgcn_global_load_lds(
                    (const GLOBAL_AS u32*)(const void*)src,
                    (LDS_AS u32*)(void*)(As + c * 1024), 16, 0, 0);
            }
#pragma unroll
            for (int bq = 0; bq < NB; ++bq) {
                const int c    = bq * 4 + wid;
                const int loff = c * 1024 + lane * 16;
                const int row  = loff >> 6;
                const int kb   = loff & 63;
                const __hip_bfloat16* src = BT + (size_t)(bn + row) * K + k0 + (kb >> 1);
                __builtin_amdgcn_global_load_lds(
                    (const GLOBAL_AS u32*)(const void*)src,
                    (LDS_AS u32*)(void*)(Bs + c * 1024), 16, 0, 0);
            }
            __syncthreads();

            bf16x8 af[FM], bfq[FN];
#pragma unroll
            for (int ii = 0; ii < FM; ++ii) {
                const int row = wm * WM + ii * 16 + (lane & 15);
                af[ii] = *(const bf16x8*)(As + row * 64 + (lane >> 4) * 16);
            }
#pragma unroll
            for (int j = 0; j < FN; ++j) {
                const int col = wn * WN + j * 16 + (lane & 15);
                bfq[j] = *(const bf16x8*)(Bs + col * 64 + (lane >> 4) * 16);
            }
#pragma unroll
            for (int ii = 0; ii < FM; ++ii)
#pragma unroll
                for (int j = 0; j < FN; ++j)
                    acc[ii][j] = __builtin_amdgcn_mfma_f32_16x16x32_bf16(
                        af[ii], bfq[j], acc[ii][j], 0, 0, 0);
            __syncthreads();
        }

#pragma unroll
        for (int ii = 0; ii < FM; ++ii) {
            const int row0 = bm + wm * WM + ii * 16 + (lane >> 4) * 4;
#pragma unroll
            for (int j = 0; j < FN; ++j) {
                const int col = bn + wn * WN + j * 16 + (lane & 15);
#pragma unroll
                for (int rr = 0; rr < 4; ++rr) {
                    const int row = row0 + rr;
                    float v = acc[ii][j][rr];
                    if (MODE == 0) {
                        v = 0.5f * v * (1.0f + erff(v * 0.70710678118654752440f));
                        ((__hip_bfloat16*)Cout)[(size_t)row * N + col] = __float2bfloat16(v);
                    } else {
                        const float vv = v + Res[(size_t)row * N + col];
                        ((float*)Cout)[(size_t)row * N + col] = vv;
                        Cbf[(size_t)row * N + col] = __float2bfloat16(vv);
                    }
                }
            }
        }
    }
}

// ---------------------------------------------------------------------------
// Per-token gather: x_new[t] = x[t] + sum_{w in list[t]} words_bf16[w].
// ---------------------------------------------------------------------------
__device__ inline void acc_bf8(f32x4& a, f32x4& b, bf16x8 r)
{
    a.x += __uint_as_float(((u32)(unsigned short)r[0]) << 16);
    a.y += __uint_as_float(((u32)(unsigned short)r[1]) << 16);
    a.z += __uint_as_float(((u32)(unsigned short)r[2]) << 16);
    a.w += __uint_as_float(((u32)(unsigned short)r[3]) << 16);
    b.x += __uint_as_float(((u32)(unsigned short)r[4]) << 16);
    b.y += __uint_as_float(((u32)(unsigned short)r[5]) << 16);
    b.z += __uint_as_float(((u32)(unsigned short)r[6]) << 16);
    b.w += __uint_as_float(((u32)(unsigned short)r[7]) << 16);
}

__global__ __launch_bounds__(256) void scatter_add_kernel(
    const float* __restrict__ x, const __hip_bfloat16* __restrict__ words_bf,
    const int* __restrict__ counts, const unsigned short* __restrict__ lists,
    float* __restrict__ x_new)
{
    const int t = __builtin_amdgcn_readfirstlane(
        (int)blockIdx.x * 4 + ((int)threadIdx.x >> 6));
    const int lane = threadIdx.x & 63;
    const size_t base = (size_t)t * N_EMBD + lane * 8;

    f32x4 s0a = __builtin_nontemporal_load((const f32x4*)(x + base));
    f32x4 s0b = __builtin_nontemporal_load((const f32x4*)(x + base + 4));
    f32x4 s1a = {0.f, 0.f, 0.f, 0.f};
    f32x4 s1b = {0.f, 0.f, 0.f, 0.f};

    const int cnt = min(counts[t], CAP);
    const unsigned short* lst = &lists[(size_t)t * CAP];

    int i = 0;
    for (; i + 2 <= cnt; i += 2) {
        const bf16x8 r0 = *(const bf16x8*)(words_bf + (size_t)lst[i]     * N_EMBD + lane * 8);
        const bf16x8 r1 = *(const bf16x8*)(words_bf + (size_t)lst[i + 1] * N_EMBD + lane * 8);
        acc_bf8(s0a, s0b, r0);
        acc_bf8(s1a, s1b, r1);
    }
    if (i < cnt) {
        const bf16x8 r0 = *(const bf16x8*)(words_bf + (size_t)lst[i] * N_EMBD + lane * 8);
        acc_bf8(s0a, s0b, r0);
    }
    s0a += s1a; s0b += s1b;
    __builtin_nontemporal_store(s0a, (f32x4*)(x_new + base));
    __builtin_nontemporal_store(s0b, (f32x4*)(x_new + base + 4));
}

// ---------------------------------------------------------------------------
extern "C" void kernel_launch(void* const* d_in, const int* in_sizes, int n_in,
                              void* d_out, int out_size, void* d_ws, size_t ws_size,
                              hipStream_t stream)
{
    const float* in_words = (const float*)d_in[0];
    const float* x        = (const float*)d_in[1];
    const int*   mask     = (const int*)d_in[2];   // numpy bool -> int32 per harness
    const float* W_fc     = (const float*)d_in[3];
    const float* W_proj   = (const float*)d_in[4];

    float* out_words = (float*)d_out;                        // [4096, 512]
    float* out_x     = out_words + (size_t)W_WORDS * N_EMBD; // [32768, 512]

    char* ws = (char*)d_ws;
    __hip_bfloat16* words_bf = (__hip_bfloat16*)(ws);                    //  4 MiB
    __hip_bfloat16* WfcT     = (__hip_bfloat16*)(ws + (4u << 20));       //  2 MiB [2048][512]
    __hip_bfloat16* WprojT   = (__hip_bfloat16*)(ws + (6u << 20));       //  2 MiB [512][2048]
    __hip_bfloat16* h_bf     = (__hip_bfloat16*)(ws + (8u << 20));       // 16 MiB [4096][2048]
    __hip_bfloat16* wout_bf  = (__hip_bfloat16*)(ws + (24u << 20));      //  4 MiB bf16 shadow
    int*            counts   = (int*)(ws + (28u << 20));                 // 132 KiB zeroed region
    int*            ctrA     = counts + T_TOKENS;                        // steal counters
    int*            ctrB     = counts + T_TOKENS + 1;
    unsigned short* lists    = (unsigned short*)(ws + (28u << 20) + (33792 * 4)); // 4 MiB

    // Phase 0: prep (convert + transposes + zero counts/ctrs)
    prep_kernel<<<3105, 256, 0, stream>>>(in_words, words_bf, W_fc, WfcT,
                                          W_proj, WprojT, counts);

    // Phase 1: steal-mix of GEMM1+GELU (512 tiles) and scan subs [0, 14400)
    {
        const int nTiles = (N_HIDDEN / 128) * (W_WORDS / 128);   // 512
        const int nBig   = SCAN_SUB_A / 4;                       // 3600
        mega_kernel<128, 128, 0><<<4096, 256, 0, stream>>>(
            words_bf, WfcT, nullptr, h_bf, nullptr,
            W_WORDS, N_HIDDEN, N_EMBD, nTiles, N_HIDDEN / 128,
            mask, counts, lists, 0, nBig, ctrA);
    }

    // Phase 2: steal-mix of GEMM2+residual (512 tiles) and scan subs [14400, 32768)
    {
        const int nTiles = (N_EMBD / 64) * (W_WORDS / 64);       // 512
        const int nBig   = (32768 - SCAN_SUB_A) / 4;             // 4592
        mega_kernel<64, 64, 1><<<4096, 256, 0, stream>>>(
            h_bf, WprojT, in_words, out_words, wout_bf,
            W_WORDS, N_EMBD, N_HIDDEN, nTiles, N_EMBD / 64,
            mask, counts, lists, SCAN_SUB_A, nBig, ctrB);
    }

    // Phase 3: gather-accumulate into x_new (bf16 gathers)
    scatter_add_kernel<<<T_TOKENS / 4, 256, 0, stream>>>(
        x, wout_bf, counts, lists, out_x);
}

// Round 9
// 209.870 us; speedup vs baseline: 1.7897x; 1.7897x over previous
//
#include <hip/hip_runtime.h>
#include <hip/hip_bf16.h>
#include <math.h>

#define W_WORDS  4096
#define T_TOKENS 32768
#define N_EMBD   512
#define N_HIDDEN 2048
#define CAP      64   // max words per token (Binomial(4096,0.004): mean 16.4)

typedef __attribute__((ext_vector_type(8))) short bf16x8;   // MFMA A/B frag (4 VGPR)
typedef __attribute__((ext_vector_type(4))) float f32x4;    // MFMA C/D frag
typedef __attribute__((ext_vector_type(4))) int   i32x4;
typedef unsigned int u32;

#define GLOBAL_AS __attribute__((address_space(1)))
#define LDS_AS    __attribute__((address_space(3)))

// ---------------------------------------------------------------------------
// Prep kernel: convert in_words->bf16, transpose W_fc / W_proj, zero counts.
//   blocks [0,1024)     : convert words (8 f32/thread)
//   blocks [1024,2048)  : transpose W_fc   [512][2048] -> [2048][512]
//   blocks [2048,3072)  : transpose W_proj [2048][512] -> [512][2048]
//   blocks [3072,3104)  : zero counts
// ---------------------------------------------------------------------------
__global__ __launch_bounds__(256) void prep_kernel(
    const float* __restrict__ in_words, __hip_bfloat16* __restrict__ words_bf,
    const float* __restrict__ W_fc,     __hip_bfloat16* __restrict__ WfcT,
    const float* __restrict__ W_proj,   __hip_bfloat16* __restrict__ WprojT,
    int* __restrict__ counts)
{
    __shared__ float tile[32][33];
    const int b = blockIdx.x;

    if (b < 1024) {                       // convert in_words -> bf16
        const size_t gid = (size_t)b * 256 + threadIdx.x;
        const float4 a0 = ((const float4*)in_words)[2 * gid];
        const float4 a1 = ((const float4*)in_words)[2 * gid + 1];
        union { __hip_bfloat16 t[8]; bf16x8 v; } u;
        u.t[0] = __float2bfloat16(a0.x); u.t[1] = __float2bfloat16(a0.y);
        u.t[2] = __float2bfloat16(a0.z); u.t[3] = __float2bfloat16(a0.w);
        u.t[4] = __float2bfloat16(a1.x); u.t[5] = __float2bfloat16(a1.y);
        u.t[6] = __float2bfloat16(a1.z); u.t[7] = __float2bfloat16(a1.w);
        *(bf16x8*)(words_bf + 8 * gid) = u.v;
        return;
    }
    if (b < 3072) {                       // transposes
        const float* in;  __hip_bfloat16* out; int R, C, bx, by;
        if (b < 2048) { in = W_fc;   out = WfcT;   R = N_EMBD;   C = N_HIDDEN;
                        const int l = b - 1024; bx = l & 63; by = l >> 6; }
        else          { in = W_proj; out = WprojT; R = N_HIDDEN; C = N_EMBD;
                        const int l = b - 2048; bx = l & 15; by = l >> 4; }
        const int tx = threadIdx.x & 31, ty = threadIdx.x >> 5;
        const int r0 = by * 32, c0 = bx * 32;
#pragma unroll
        for (int i = 0; i < 4; ++i) {
            const int r = ty + i * 8;
            tile[r][tx] = in[(size_t)(r0 + r) * C + c0 + tx];
        }
        __syncthreads();
#pragma unroll
        for (int i = 0; i < 4; ++i) {
            const int r = ty + i * 8;
            out[(size_t)(c0 + r) * R + r0 + tx] = __float2bfloat16(tile[tx][r]);
        }
        return;
    }
    const int idx = (b - 3072) * 1024 + (int)threadIdx.x * 4;
    *(i32x4*)(counts + idx) = (i32x4){0, 0, 0, 0};
}

// ---------------------------------------------------------------------------
// bf16 MFMA GEMM: C[M,N] = A[M,K] @ BT[N,K]^T. 4 waves (2x2), 16x16x32 MFMA,
// global_load_lds width-16 staging into linear LDS.
// KSUB 32-wide k-chunks staged as SEPARATE 64B-row sub-tiles per barrier-pair
// (halves barrier count vs BK=32 without creating 128B-row bank conflicts).
// MODE 0: C = bf16(gelu_exact(acc))
// MODE 1: Cf32 = acc + Res, AND Cbf = bf16(acc + Res)  (shadow for gather)
// ---------------------------------------------------------------------------
template <int BM, int BN, int MODE, int KSUB>
__global__ __launch_bounds__(256) void gemm_bf16_mfma_kernel(
    const __hip_bfloat16* __restrict__ A,
    const __hip_bfloat16* __restrict__ BT,
    const float* __restrict__ Res,
    void* __restrict__ Cout,
    __hip_bfloat16* __restrict__ Cbf,
    int M, int N, int K)
{
    constexpr int BK = 32 * KSUB;
    constexpr int WM = BM / 2, WN = BN / 2;
    constexpr int FM = WM / 16, FN = WN / 16;
    constexpr int NA = (BM * 64) / 4096;      // issues per 32-k sub-tile (256 thr x 16B)
    constexpr int NB = (BN * 64) / 4096;

    __shared__ __align__(16) char smem[(BM + BN) * 64 * KSUB];
    char* As = smem;                          // KSUB sub-tiles of [BM][64B]
    char* Bs = smem + BM * 64 * KSUB;         // KSUB sub-tiles of [BN][64B]

    const int tid  = threadIdx.x;
    const int lane = tid & 63;
    const int wid  = tid >> 6;
    const int wm   = wid >> 1, wn = wid & 1;
    const int bm   = blockIdx.y * BM;
    const int bn   = blockIdx.x * BN;

    f32x4 acc[FM][FN] = {};

    for (int k0 = 0; k0 < K; k0 += BK) {
#pragma unroll
        for (int ks = 0; ks < KSUB; ++ks) {
#pragma unroll
            for (int a = 0; a < NA; ++a) {
                const int c    = a * 4 + wid;
                const int loff = c * 1024 + lane * 16;
                const int row  = loff >> 6;
                const int kb   = loff & 63;
                const __hip_bfloat16* src =
                    A + (size_t)(bm + row) * K + k0 + ks * 32 + (kb >> 1);
                __builtin_amdgcn_global_load_lds(
                    (const GLOBAL_AS u32*)(const void*)src,
                    (LDS_AS u32*)(void*)(As + ks * BM * 64 + c * 1024), 16, 0, 0);
            }
#pragma unroll
            for (int bq = 0; bq < NB; ++bq) {
                const int c    = bq * 4 + wid;
                const int loff = c * 1024 + lane * 16;
                const int row  = loff >> 6;
                const int kb   = loff & 63;
                const __hip_bfloat16* src =
                    BT + (size_t)(bn + row) * K + k0 + ks * 32 + (kb >> 1);
                __builtin_amdgcn_global_load_lds(
                    (const GLOBAL_AS u32*)(const void*)src,
                    (LDS_AS u32*)(void*)(Bs + ks * BN * 64 + c * 1024), 16, 0, 0);
            }
        }
        __syncthreads();

#pragma unroll
        for (int ks = 0; ks < KSUB; ++ks) {
            bf16x8 af[FM], bfq[FN];
#pragma unroll
            for (int i = 0; i < FM; ++i) {
                const int row = wm * WM + i * 16 + (lane & 15);
                af[i] = *(const bf16x8*)(As + ks * BM * 64 + row * 64 + (lane >> 4) * 16);
            }
#pragma unroll
            for (int j = 0; j < FN; ++j) {
                const int col = wn * WN + j * 16 + (lane & 15);
                bfq[j] = *(const bf16x8*)(Bs + ks * BN * 64 + col * 64 + (lane >> 4) * 16);
            }
#pragma unroll
            for (int i = 0; i < FM; ++i)
#pragma unroll
                for (int j = 0; j < FN; ++j)
                    acc[i][j] = __builtin_amdgcn_mfma_f32_16x16x32_bf16(
                        af[i], bfq[j], acc[i][j], 0, 0, 0);
        }
        __syncthreads();
    }

#pragma unroll
    for (int i = 0; i < FM; ++i) {
        const int row0 = bm + wm * WM + i * 16 + (lane >> 4) * 4;
#pragma unroll
        for (int j = 0; j < FN; ++j) {
            const int col = bn + wn * WN + j * 16 + (lane & 15);
#pragma unroll
            for (int r = 0; r < 4; ++r) {
                const int row = row0 + r;
                float v = acc[i][j][r];
                if (MODE == 0) {
                    v = 0.5f * v * (1.0f + erff(v * 0.70710678118654752440f));
                    ((__hip_bfloat16*)Cout)[(size_t)row * N + col] = __float2bfloat16(v);
                } else {
                    const float vv = v + Res[(size_t)row * N + col];
                    ((float*)Cout)[(size_t)row * N + col] = vv;
                    Cbf[(size_t)row * N + col] = __float2bfloat16(vv);
                }
            }
        }
    }
}

// ---------------------------------------------------------------------------
// Mask scan: block covers 4096 int32 (16 KB). All 4 nt loads issued before
// any processing (guaranteed 4 in-flight -> deeper memory pipeline).
// ---------------------------------------------------------------------------
__global__ __launch_bounds__(256) void scan_kernel(
    const int* __restrict__ mask, int* __restrict__ counts,
    unsigned short* __restrict__ lists)
{
    const size_t base = (size_t)blockIdx.x * 4096 + (size_t)threadIdx.x * 4;
    i32x4 v[4];
#pragma unroll
    for (int k = 0; k < 4; ++k)
        v[k] = __builtin_nontemporal_load((const i32x4*)(mask + base + (size_t)k * 1024));

#pragma unroll
    for (int k = 0; k < 4; ++k) {
        if ((v[k].x | v[k].y | v[k].z | v[k].w) == 0) continue;
        const size_t e = base + (size_t)k * 1024;
        const int w  = (int)(e >> 15);
        const int t0 = (int)(e & (T_TOKENS - 1));
        if (v[k].x) { const int p = atomicAdd(&counts[t0+0], 1); if (p < CAP) lists[(size_t)(t0+0)*CAP+p] = (unsigned short)w; }
        if (v[k].y) { const int p = atomicAdd(&counts[t0+1], 1); if (p < CAP) lists[(size_t)(t0+1)*CAP+p] = (unsigned short)w; }
        if (v[k].z) { const int p = atomicAdd(&counts[t0+2], 1); if (p < CAP) lists[(size_t)(t0+2)*CAP+p] = (unsigned short)w; }
        if (v[k].w) { const int p = atomicAdd(&counts[t0+3], 1); if (p < CAP) lists[(size_t)(t0+3)*CAP+p] = (unsigned short)w; }
    }
}

// ---------------------------------------------------------------------------
// Per-token gather: x_new[t] = x[t] + sum_{w in list[t]} words_bf16[w].
// bf16 shadow gathers (L2-resident 4 MiB); nt for x/x_new; 2 acc chains.
// ---------------------------------------------------------------------------
__device__ inline void acc_bf8(f32x4& a, f32x4& b, bf16x8 r)
{
    a.x += __uint_as_float(((u32)(unsigned short)r[0]) << 16);
    a.y += __uint_as_float(((u32)(unsigned short)r[1]) << 16);
    a.z += __uint_as_float(((u32)(unsigned short)r[2]) << 16);
    a.w += __uint_as_float(((u32)(unsigned short)r[3]) << 16);
    b.x += __uint_as_float(((u32)(unsigned short)r[4]) << 16);
    b.y += __uint_as_float(((u32)(unsigned short)r[5]) << 16);
    b.z += __uint_as_float(((u32)(unsigned short)r[6]) << 16);
    b.w += __uint_as_float(((u32)(unsigned short)r[7]) << 16);
}

__global__ __launch_bounds__(256) void scatter_add_kernel(
    const float* __restrict__ x, const __hip_bfloat16* __restrict__ words_bf,
    const int* __restrict__ counts, const unsigned short* __restrict__ lists,
    float* __restrict__ x_new)
{
    const int t = __builtin_amdgcn_readfirstlane(
        (int)blockIdx.x * 4 + ((int)threadIdx.x >> 6));
    const int lane = threadIdx.x & 63;
    const size_t base = (size_t)t * N_EMBD + lane * 8;

    f32x4 s0a = __builtin_nontemporal_load((const f32x4*)(x + base));
    f32x4 s0b = __builtin_nontemporal_load((const f32x4*)(x + base + 4));
    f32x4 s1a = {0.f, 0.f, 0.f, 0.f};
    f32x4 s1b = {0.f, 0.f, 0.f, 0.f};

    const int cnt = min(counts[t], CAP);
    const unsigned short* lst = &lists[(size_t)t * CAP];

    int i = 0;
    for (; i + 2 <= cnt; i += 2) {
        const bf16x8 r0 = *(const bf16x8*)(words_bf + (size_t)lst[i]     * N_EMBD + lane * 8);
        const bf16x8 r1 = *(const bf16x8*)(words_bf + (size_t)lst[i + 1] * N_EMBD + lane * 8);
        acc_bf8(s0a, s0b, r0);
        acc_bf8(s1a, s1b, r1);
    }
    if (i < cnt) {
        const bf16x8 r0 = *(const bf16x8*)(words_bf + (size_t)lst[i] * N_EMBD + lane * 8);
        acc_bf8(s0a, s0b, r0);
    }
    s0a += s1a; s0b += s1b;
    __builtin_nontemporal_store(s0a, (f32x4*)(x_new + base));
    __builtin_nontemporal_store(s0b, (f32x4*)(x_new + base + 4));
}

// ---------------------------------------------------------------------------
extern "C" void kernel_launch(void* const* d_in, const int* in_sizes, int n_in,
                              void* d_out, int out_size, void* d_ws, size_t ws_size,
                              hipStream_t stream)
{
    const float* in_words = (const float*)d_in[0];
    const float* x        = (const float*)d_in[1];
    const int*   mask     = (const int*)d_in[2];   // numpy bool -> int32 per harness
    const float* W_fc     = (const float*)d_in[3];
    const float* W_proj   = (const float*)d_in[4];

    float* out_words = (float*)d_out;                        // [4096, 512]
    float* out_x     = out_words + (size_t)W_WORDS * N_EMBD; // [32768, 512]

    char* ws = (char*)d_ws;
    __hip_bfloat16* words_bf = (__hip_bfloat16*)(ws);                    //  4 MiB
    __hip_bfloat16* WfcT     = (__hip_bfloat16*)(ws + (4u << 20));       //  2 MiB [2048][512]
    __hip_bfloat16* WprojT   = (__hip_bfloat16*)(ws + (6u << 20));       //  2 MiB [512][2048]
    __hip_bfloat16* h_bf     = (__hip_bfloat16*)(ws + (8u << 20));       // 16 MiB [4096][2048]
    __hip_bfloat16* wout_bf  = (__hip_bfloat16*)(ws + (24u << 20));      //  4 MiB bf16 shadow
    int*            counts   = (int*)(ws + (28u << 20));                 // 128 KiB
    unsigned short* lists    = (unsigned short*)(ws + (28u << 20) + T_TOKENS * 4); // 4 MiB

    // Phase 0: prep (convert + transposes + zero counts)
    prep_kernel<<<3104, 256, 0, stream>>>(in_words, words_bf, W_fc, WfcT,
                                          W_proj, WprojT, counts);

    // Phase 1: GEMM1+GELU: h_bf = gelu(words_bf @ W_fc)  [4096, 2048]
    gemm_bf16_mfma_kernel<128, 128, 0, 2>
        <<<dim3(N_HIDDEN / 128, W_WORDS / 128), 256, 0, stream>>>(
            words_bf, WfcT, nullptr, h_bf, nullptr, W_WORDS, N_HIDDEN, N_EMBD);

    // Phase 2: GEMM2+residual: out_words (f32) + wout_bf (bf16 shadow)
    gemm_bf16_mfma_kernel<64, 64, 1, 2>
        <<<dim3(N_EMBD / 64, W_WORDS / 64), 256, 0, stream>>>(
            h_bf, WprojT, in_words, out_words, wout_bf, W_WORDS, N_EMBD, N_HIDDEN);

    // Phase 3: mask scan -> per-token word lists
    scan_kernel<<<32768, 256, 0, stream>>>(mask, counts, lists);

    // Phase 4: gather-accumulate into x_new (bf16 gathers)
    scatter_add_kernel<<<T_TOKENS / 4, 256, 0, stream>>>(
        x, wout_bf, counts, lists, out_x);
}

// Round 10
// 200.964 us; speedup vs baseline: 1.8690x; 1.0443x over previous
//
#include <hip/hip_runtime.h>
#include <hip/hip_bf16.h>
#include <math.h>

#define W_WORDS  4096
#define T_TOKENS 32768
#define N_EMBD   512
#define N_HIDDEN 2048
#define CAP      64   // max words per token (Binomial(4096,0.004): mean 16.4)

typedef __attribute__((ext_vector_type(8))) short bf16x8;   // MFMA A/B frag (4 VGPR)
typedef __attribute__((ext_vector_type(4))) float f32x4;    // MFMA C/D frag
typedef __attribute__((ext_vector_type(4))) int   i32x4;
typedef unsigned int u32;

#define GLOBAL_AS __attribute__((address_space(1)))
#define LDS_AS    __attribute__((address_space(3)))

// ---------------------------------------------------------------------------
// Prep kernel: convert in_words->bf16, transpose W_fc / W_proj, zero counts.
// ---------------------------------------------------------------------------
__global__ __launch_bounds__(256) void prep_kernel(
    const float* __restrict__ in_words, __hip_bfloat16* __restrict__ words_bf,
    const float* __restrict__ W_fc,     __hip_bfloat16* __restrict__ WfcT,
    const float* __restrict__ W_proj,   __hip_bfloat16* __restrict__ WprojT,
    int* __restrict__ counts)
{
    __shared__ float tile[32][33];
    const int b = blockIdx.x;

    if (b < 1024) {                       // convert in_words -> bf16
        const size_t gid = (size_t)b * 256 + threadIdx.x;
        const float4 a0 = ((const float4*)in_words)[2 * gid];
        const float4 a1 = ((const float4*)in_words)[2 * gid + 1];
        union { __hip_bfloat16 t[8]; bf16x8 v; } u;
        u.t[0] = __float2bfloat16(a0.x); u.t[1] = __float2bfloat16(a0.y);
        u.t[2] = __float2bfloat16(a0.z); u.t[3] = __float2bfloat16(a0.w);
        u.t[4] = __float2bfloat16(a1.x); u.t[5] = __float2bfloat16(a1.y);
        u.t[6] = __float2bfloat16(a1.z); u.t[7] = __float2bfloat16(a1.w);
        *(bf16x8*)(words_bf + 8 * gid) = u.v;
        return;
    }
    if (b < 3072) {                       // transposes
        const float* in;  __hip_bfloat16* out; int R, C, bx, by;
        if (b < 2048) { in = W_fc;   out = WfcT;   R = N_EMBD;   C = N_HIDDEN;
                        const int l = b - 1024; bx = l & 63; by = l >> 6; }
        else          { in = W_proj; out = WprojT; R = N_HIDDEN; C = N_EMBD;
                        const int l = b - 2048; bx = l & 15; by = l >> 4; }
        const int tx = threadIdx.x & 31, ty = threadIdx.x >> 5;
        const int r0 = by * 32, c0 = bx * 32;
#pragma unroll
        for (int i = 0; i < 4; ++i) {
            const int r = ty + i * 8;
            tile[r][tx] = in[(size_t)(r0 + r) * C + c0 + tx];
        }
        __syncthreads();
#pragma unroll
        for (int i = 0; i < 4; ++i) {
            const int r = ty + i * 8;
            out[(size_t)(c0 + r) * R + r0 + tx] = __float2bfloat16(tile[tx][r]);
        }
        return;
    }
    const int idx = (b - 3072) * 1024 + (int)threadIdx.x * 4;
    *(i32x4*)(counts + idx) = (i32x4){0, 0, 0, 0};
}

// ---------------------------------------------------------------------------
// bf16 MFMA GEMM: C[M,N] = A[M,K] @ BT[N,K]^T. 4 waves (2x2), 16x16x32 MFMA,
// global_load_lds width-16 staging into linear LDS.
// KSUB separate 32-k sub-tiles per barrier-pair (BK = 32*KSUB).
// 1D grid, XCD-chunked tile mapping: g = (bid&7)*(nTiles/8) + (bid>>3),
// row-major over (M-blocks x N-blocks) -> each XCD owns a contiguous band of
// row-blocks; A-panels + full BT fit its 4 MiB L2 (bijective: nTiles%8==0).
// MODE 0: C = bf16(gelu_exact(acc))
// MODE 1: Cf32 = acc + Res, AND Cbf = bf16(acc + Res)  (shadow for gather)
// ---------------------------------------------------------------------------
template <int BM, int BN, int MODE, int KSUB, int GRIDN, int NTILES>
__global__ __launch_bounds__(256) void gemm_bf16_mfma_kernel(
    const __hip_bfloat16* __restrict__ A,
    const __hip_bfloat16* __restrict__ BT,
    const float* __restrict__ Res,
    void* __restrict__ Cout,
    __hip_bfloat16* __restrict__ Cbf,
    int M, int N, int K)
{
    constexpr int BK = 32 * KSUB;
    constexpr int WM = BM / 2, WN = BN / 2;
    constexpr int FM = WM / 16, FN = WN / 16;
    constexpr int NA = (BM * 64) / 4096;      // issues per 32-k sub-tile
    constexpr int NB = (BN * 64) / 4096;

    __shared__ __align__(16) char smem[(BM + BN) * 64 * KSUB];
    char* As = smem;                          // KSUB sub-tiles of [BM][64B]
    char* Bs = smem + BM * 64 * KSUB;         // KSUB sub-tiles of [BN][64B]

    const int tid  = threadIdx.x;
    const int lane = tid & 63;
    const int wid  = tid >> 6;
    const int wm   = wid >> 1, wn = wid & 1;

    const int bid = (int)blockIdx.x;
    const int g   = (bid & 7) * (NTILES / 8) + (bid >> 3);  // XCD-chunked remap
    const int bm  = (g / GRIDN) * BM;
    const int bn  = (g % GRIDN) * BN;

    f32x4 acc[FM][FN] = {};

    for (int k0 = 0; k0 < K; k0 += BK) {
#pragma unroll
        for (int ks = 0; ks < KSUB; ++ks) {
#pragma unroll
            for (int a = 0; a < NA; ++a) {
                const int c    = a * 4 + wid;
                const int loff = c * 1024 + lane * 16;
                const int row  = loff >> 6;
                const int kb   = loff & 63;
                const __hip_bfloat16* src =
                    A + (size_t)(bm + row) * K + k0 + ks * 32 + (kb >> 1);
                __builtin_amdgcn_global_load_lds(
                    (const GLOBAL_AS u32*)(const void*)src,
                    (LDS_AS u32*)(void*)(As + ks * BM * 64 + c * 1024), 16, 0, 0);
            }
#pragma unroll
            for (int bq = 0; bq < NB; ++bq) {
                const int c    = bq * 4 + wid;
                const int loff = c * 1024 + lane * 16;
                const int row  = loff >> 6;
                const int kb   = loff & 63;
                const __hip_bfloat16* src =
                    BT + (size_t)(bn + row) * K + k0 + ks * 32 + (kb >> 1);
                __builtin_amdgcn_global_load_lds(
                    (const GLOBAL_AS u32*)(const void*)src,
                    (LDS_AS u32*)(void*)(Bs + ks * BN * 64 + c * 1024), 16, 0, 0);
            }
        }
        __syncthreads();

#pragma unroll
        for (int ks = 0; ks < KSUB; ++ks) {
            bf16x8 af[FM], bfq[FN];
#pragma unroll
            for (int i = 0; i < FM; ++i) {
                const int row = wm * WM + i * 16 + (lane & 15);
                af[i] = *(const bf16x8*)(As + ks * BM * 64 + row * 64 + (lane >> 4) * 16);
            }
#pragma unroll
            for (int j = 0; j < FN; ++j) {
                const int col = wn * WN + j * 16 + (lane & 15);
                bfq[j] = *(const bf16x8*)(Bs + ks * BN * 64 + col * 64 + (lane >> 4) * 16);
            }
#pragma unroll
            for (int i = 0; i < FM; ++i)
#pragma unroll
                for (int j = 0; j < FN; ++j)
                    acc[i][j] = __builtin_amdgcn_mfma_f32_16x16x32_bf16(
                        af[i], bfq[j], acc[i][j], 0, 0, 0);
        }
        __syncthreads();
    }

#pragma unroll
    for (int i = 0; i < FM; ++i) {
        const int row0 = bm + wm * WM + i * 16 + (lane >> 4) * 4;
#pragma unroll
        for (int j = 0; j < FN; ++j) {
            const int col = bn + wn * WN + j * 16 + (lane & 15);
#pragma unroll
            for (int r = 0; r < 4; ++r) {
                const int row = row0 + r;
                float v = acc[i][j][r];
                if (MODE == 0) {
                    v = 0.5f * v * (1.0f + erff(v * 0.70710678118654752440f));
                    ((__hip_bfloat16*)Cout)[(size_t)row * N + col] = __float2bfloat16(v);
                } else {
                    const float vv = v + Res[(size_t)row * N + col];
                    ((float*)Cout)[(size_t)row * N + col] = vv;
                    Cbf[(size_t)row * N + col] = __float2bfloat16(vv);
                }
            }
        }
    }
}

// ---------------------------------------------------------------------------
// Mask scan: block covers 4096 int32 (16 KB); 4 nt int4 loads issued up front.
// ---------------------------------------------------------------------------
__global__ __launch_bounds__(256) void scan_kernel(
    const int* __restrict__ mask, int* __restrict__ counts,
    unsigned short* __restrict__ lists)
{
    const size_t base = (size_t)blockIdx.x * 4096 + (size_t)threadIdx.x * 4;
    i32x4 v[4];
#pragma unroll
    for (int k = 0; k < 4; ++k)
        v[k] = __builtin_nontemporal_load((const i32x4*)(mask + base + (size_t)k * 1024));

#pragma unroll
    for (int k = 0; k < 4; ++k) {
        if ((v[k].x | v[k].y | v[k].z | v[k].w) == 0) continue;
        const size_t e = base + (size_t)k * 1024;
        const int w  = (int)(e >> 15);
        const int t0 = (int)(e & (T_TOKENS - 1));
        if (v[k].x) { const int p = atomicAdd(&counts[t0+0], 1); if (p < CAP) lists[(size_t)(t0+0)*CAP+p] = (unsigned short)w; }
        if (v[k].y) { const int p = atomicAdd(&counts[t0+1], 1); if (p < CAP) lists[(size_t)(t0+1)*CAP+p] = (unsigned short)w; }
        if (v[k].z) { const int p = atomicAdd(&counts[t0+2], 1); if (p < CAP) lists[(size_t)(t0+2)*CAP+p] = (unsigned short)w; }
        if (v[k].w) { const int p = atomicAdd(&counts[t0+3], 1); if (p < CAP) lists[(size_t)(t0+3)*CAP+p] = (unsigned short)w; }
    }
}

// ---------------------------------------------------------------------------
// Per-token gather: x_new[t] = x[t] + sum_{w in list[t]} words_bf16[w].
// ---------------------------------------------------------------------------
__device__ inline void acc_bf8(f32x4& a, f32x4& b, bf16x8 r)
{
    a.x += __uint_as_float(((u32)(unsigned short)r[0]) << 16);
    a.y += __uint_as_float(((u32)(unsigned short)r[1]) << 16);
    a.z += __uint_as_float(((u32)(unsigned short)r[2]) << 16);
    a.w += __uint_as_float(((u32)(unsigned short)r[3]) << 16);
    b.x += __uint_as_float(((u32)(unsigned short)r[4]) << 16);
    b.y += __uint_as_float(((u32)(unsigned short)r[5]) << 16);
    b.z += __uint_as_float(((u32)(unsigned short)r[6]) << 16);
    b.w += __uint_as_float(((u32)(unsigned short)r[7]) << 16);
}

__global__ __launch_bounds__(256) void scatter_add_kernel(
    const float* __restrict__ x, const __hip_bfloat16* __restrict__ words_bf,
    const int* __restrict__ counts, const unsigned short* __restrict__ lists,
    float* __restrict__ x_new)
{
    const int t = __builtin_amdgcn_readfirstlane(
        (int)blockIdx.x * 4 + ((int)threadIdx.x >> 6));
    const int lane = threadIdx.x & 63;
    const size_t base = (size_t)t * N_EMBD + lane * 8;

    f32x4 s0a = __builtin_nontemporal_load((const f32x4*)(x + base));
    f32x4 s0b = __builtin_nontemporal_load((const f32x4*)(x + base + 4));
    f32x4 s1a = {0.f, 0.f, 0.f, 0.f};
    f32x4 s1b = {0.f, 0.f, 0.f, 0.f};

    const int cnt = min(counts[t], CAP);
    const unsigned short* lst = &lists[(size_t)t * CAP];

    int i = 0;
    for (; i + 2 <= cnt; i += 2) {
        const bf16x8 r0 = *(const bf16x8*)(words_bf + (size_t)lst[i]     * N_EMBD + lane * 8);
        const bf16x8 r1 = *(const bf16x8*)(words_bf + (size_t)lst[i + 1] * N_EMBD + lane * 8);
        acc_bf8(s0a, s0b, r0);
        acc_bf8(s1a, s1b, r1);
    }
    if (i < cnt) {
        const bf16x8 r0 = *(const bf16x8*)(words_bf + (size_t)lst[i] * N_EMBD + lane * 8);
        acc_bf8(s0a, s0b, r0);
    }
    s0a += s1a; s0b += s1b;
    __builtin_nontemporal_store(s0a, (f32x4*)(x_new + base));
    __builtin_nontemporal_store(s0b, (f32x4*)(x_new + base + 4));
}

// ---------------------------------------------------------------------------
extern "C" void kernel_launch(void* const* d_in, const int* in_sizes, int n_in,
                              void* d_out, int out_size, void* d_ws, size_t ws_size,
                              hipStream_t stream)
{
    const float* in_words = (const float*)d_in[0];
    const float* x        = (const float*)d_in[1];
    const int*   mask     = (const int*)d_in[2];   // numpy bool -> int32 per harness
    const float* W_fc     = (const float*)d_in[3];
    const float* W_proj   = (const float*)d_in[4];

    float* out_words = (float*)d_out;                        // [4096, 512]
    float* out_x     = out_words + (size_t)W_WORDS * N_EMBD; // [32768, 512]

    char* ws = (char*)d_ws;
    __hip_bfloat16* words_bf = (__hip_bfloat16*)(ws);                    //  4 MiB
    __hip_bfloat16* WfcT     = (__hip_bfloat16*)(ws + (4u << 20));       //  2 MiB [2048][512]
    __hip_bfloat16* WprojT   = (__hip_bfloat16*)(ws + (6u << 20));       //  2 MiB [512][2048]
    __hip_bfloat16* h_bf     = (__hip_bfloat16*)(ws + (8u << 20));       // 16 MiB [4096][2048]
    __hip_bfloat16* wout_bf  = (__hip_bfloat16*)(ws + (24u << 20));      //  4 MiB bf16 shadow
    int*            counts   = (int*)(ws + (28u << 20));                 // 128 KiB
    unsigned short* lists    = (unsigned short*)(ws + (28u << 20) + T_TOKENS * 4); // 4 MiB

    // Phase 0: prep (convert + transposes + zero counts)
    prep_kernel<<<3104, 256, 0, stream>>>(in_words, words_bf, W_fc, WfcT,
                                          W_proj, WprojT, counts);

    // Phase 1: GEMM1+GELU: h_bf = gelu(words_bf @ W_fc)  [4096, 2048]
    // 512 tiles = 32 Mblk x 16 Nblk, KSUB=4 (BK=128), XCD-chunked mapping
    gemm_bf16_mfma_kernel<128, 128, 0, 4, 16, 512>
        <<<512, 256, 0, stream>>>(
            words_bf, WfcT, nullptr, h_bf, nullptr, W_WORDS, N_HIDDEN, N_EMBD);

    // Phase 2: GEMM2+residual: out_words (f32) + wout_bf (bf16 shadow)
    // 512 tiles = 64 Mblk x 8 Nblk, KSUB=4 (BK=128), XCD-chunked mapping
    gemm_bf16_mfma_kernel<64, 64, 1, 4, 8, 512>
        <<<512, 256, 0, stream>>>(
            h_bf, WprojT, in_words, out_words, wout_bf, W_WORDS, N_EMBD, N_HIDDEN);

    // Phase 3: mask scan -> per-token word lists
    scan_kernel<<<32768, 256, 0, stream>>>(mask, counts, lists);

    // Phase 4: gather-accumulate into x_new (bf16 gathers)
    scatter_add_kernel<<<T_TOKENS / 4, 256, 0, stream>>>(
        x, wout_bf, counts, lists, out_x);
}

// Round 11
// 199.287 us; speedup vs baseline: 1.8847x; 1.0084x over previous
//
#include <hip/hip_runtime.h>
#include <hip/hip_bf16.h>
#include <math.h>

#define W_WORDS  4096
#define T_TOKENS 32768
#define N_EMBD   512
#define N_HIDDEN 2048
#define CAP      64   // max words per token (Binomial(4096,0.004): mean 16.4)

typedef __attribute__((ext_vector_type(8))) short bf16x8;   // MFMA A/B frag (4 VGPR)
typedef __attribute__((ext_vector_type(4))) float f32x4;    // MFMA C/D frag
typedef __attribute__((ext_vector_type(4))) int   i32x4;
typedef unsigned int u32;

#define GLOBAL_AS __attribute__((address_space(1)))
#define LDS_AS    __attribute__((address_space(3)))

// ---------------------------------------------------------------------------
// Prep kernel: convert in_words->bf16, transpose W_fc / W_proj, zero counts.
// ---------------------------------------------------------------------------
__global__ __launch_bounds__(256) void prep_kernel(
    const float* __restrict__ in_words, __hip_bfloat16* __restrict__ words_bf,
    const float* __restrict__ W_fc,     __hip_bfloat16* __restrict__ WfcT,
    const float* __restrict__ W_proj,   __hip_bfloat16* __restrict__ WprojT,
    int* __restrict__ counts)
{
    __shared__ float tile[32][33];
    const int b = blockIdx.x;

    if (b < 1024) {                       // convert in_words -> bf16
        const size_t gid = (size_t)b * 256 + threadIdx.x;
        const float4 a0 = ((const float4*)in_words)[2 * gid];
        const float4 a1 = ((const float4*)in_words)[2 * gid + 1];
        union { __hip_bfloat16 t[8]; bf16x8 v; } u;
        u.t[0] = __float2bfloat16(a0.x); u.t[1] = __float2bfloat16(a0.y);
        u.t[2] = __float2bfloat16(a0.z); u.t[3] = __float2bfloat16(a0.w);
        u.t[4] = __float2bfloat16(a1.x); u.t[5] = __float2bfloat16(a1.y);
        u.t[6] = __float2bfloat16(a1.z); u.t[7] = __float2bfloat16(a1.w);
        *(bf16x8*)(words_bf + 8 * gid) = u.v;
        return;
    }
    if (b < 3072) {                       // transposes
        const float* in;  __hip_bfloat16* out; int R, C, bx, by;
        if (b < 2048) { in = W_fc;   out = WfcT;   R = N_EMBD;   C = N_HIDDEN;
                        const int l = b - 1024; bx = l & 63; by = l >> 6; }
        else          { in = W_proj; out = WprojT; R = N_HIDDEN; C = N_EMBD;
                        const int l = b - 2048; bx = l & 15; by = l >> 4; }
        const int tx = threadIdx.x & 31, ty = threadIdx.x >> 5;
        const int r0 = by * 32, c0 = bx * 32;
#pragma unroll
        for (int i = 0; i < 4; ++i) {
            const int r = ty + i * 8;
            tile[r][tx] = in[(size_t)(r0 + r) * C + c0 + tx];
        }
        __syncthreads();
#pragma unroll
        for (int i = 0; i < 4; ++i) {
            const int r = ty + i * 8;
            out[(size_t)(c0 + r) * R + r0 + tx] = __float2bfloat16(tile[tx][r]);
        }
        return;
    }
    const int idx = (b - 3072) * 1024 + (int)threadIdx.x * 4;
    *(i32x4*)(counts + idx) = (i32x4){0, 0, 0, 0};
}

// ---------------------------------------------------------------------------
// bf16 MFMA GEMM: C[M,N] = A[M,K] @ BT[N,K]^T.
// 512 threads = 8 waves (WVM=2 x WVN=4) -> 4 waves/SIMD at 2 blocks/CU.
// KSUB separate 32-k sub-tiles per barrier-pair; each sub-tile is one linear
// (A || B) LDS region staged by wave-uniform global_load_lds issues
// (A/B boundary at BM*64 bytes, a multiple of 1024 -> no wave straddles).
// XCD-chunked tile map: g = (bid&7)*(NTILES/8) + bid>>3 (bijective, %8==0).
// MODE 0: C = bf16(gelu_exact(acc))
// MODE 1: Cf32 = acc + Res, AND Cbf = bf16(acc + Res)  (shadow for gather)
// ---------------------------------------------------------------------------
template <int BM, int BN, int MODE, int KSUB, int GRIDN, int NTILES>
__global__ __launch_bounds__(512) void gemm_bf16_mfma_kernel(
    const __hip_bfloat16* __restrict__ A,
    const __hip_bfloat16* __restrict__ BT,
    const float* __restrict__ Res,
    void* __restrict__ Cout,
    __hip_bfloat16* __restrict__ Cbf,
    int M, int N, int K)
{
    constexpr int NTHR   = 512;
    constexpr int WVN    = 4;                     // waves along N
    constexpr int WM     = BM / 2, WN = BN / WVN; // per-wave tile
    constexpr int FM     = WM / 16, FN = WN / 16;
    constexpr int BK     = 32 * KSUB;
    constexpr int TILE_B = (BM + BN) * 64;        // bytes per 32-k sub-tile (A||B)
    constexpr int NISS   = TILE_B / (NTHR * 16);  // staging issues per sub-tile

    __shared__ __align__(16) char smem[TILE_B * KSUB];

    const int tid  = (int)threadIdx.x;
    const int lane = tid & 63;
    const int wid  = tid >> 6;
    const int wm   = wid >> 2, wn = wid & 3;

    const int bid = (int)blockIdx.x;
    const int g   = (bid & 7) * (NTILES / 8) + (bid >> 3);
    const int bm  = (g / GRIDN) * BM;
    const int bn  = (g % GRIDN) * BN;

    f32x4 acc[FM][FN] = {};

    for (int k0 = 0; k0 < K; k0 += BK) {
#pragma unroll
        for (int ks = 0; ks < KSUB; ++ks) {
            const int kk = k0 + ks * 32;
#pragma unroll
            for (int is = 0; is < NISS; ++is) {
                const int boff = (is * NTHR + tid) * 16;   // byte off in (A||B) tile
                const __hip_bfloat16* src;
                if (boff < BM * 64) {
                    const int row = boff >> 6, kb = boff & 63;
                    src = A + (size_t)(bm + row) * K + kk + (kb >> 1);
                } else {
                    const int bo = boff - BM * 64;
                    const int row = bo >> 6, kb = bo & 63;
                    src = BT + (size_t)(bn + row) * K + kk + (kb >> 1);
                }
                __builtin_amdgcn_global_load_lds(
                    (const GLOBAL_AS u32*)(const void*)src,
                    (LDS_AS u32*)(void*)(smem + ks * TILE_B + boff), 16, 0, 0);
            }
        }
        __syncthreads();

#pragma unroll
        for (int ks = 0; ks < KSUB; ++ks) {
            char* As = smem + ks * TILE_B;
            char* Bs = As + BM * 64;
            bf16x8 af[FM], bfq[FN];
#pragma unroll
            for (int i = 0; i < FM; ++i) {
                const int row = wm * WM + i * 16 + (lane & 15);
                af[i] = *(const bf16x8*)(As + row * 64 + (lane >> 4) * 16);
            }
#pragma unroll
            for (int j = 0; j < FN; ++j) {
                const int col = wn * WN + j * 16 + (lane & 15);
                bfq[j] = *(const bf16x8*)(Bs + col * 64 + (lane >> 4) * 16);
            }
#pragma unroll
            for (int i = 0; i < FM; ++i)
#pragma unroll
                for (int j = 0; j < FN; ++j)
                    acc[i][j] = __builtin_amdgcn_mfma_f32_16x16x32_bf16(
                        af[i], bfq[j], acc[i][j], 0, 0, 0);
        }
        __syncthreads();
    }

#pragma unroll
    for (int i = 0; i < FM; ++i) {
        const int row0 = bm + wm * WM + i * 16 + (lane >> 4) * 4;
#pragma unroll
        for (int j = 0; j < FN; ++j) {
            const int col = bn + wn * WN + j * 16 + (lane & 15);
#pragma unroll
            for (int r = 0; r < 4; ++r) {
                const int row = row0 + r;
                float v = acc[i][j][r];
                if (MODE == 0) {
                    v = 0.5f * v * (1.0f + erff(v * 0.70710678118654752440f));
                    ((__hip_bfloat16*)Cout)[(size_t)row * N + col] = __float2bfloat16(v);
                } else {
                    const float vv = v + Res[(size_t)row * N + col];
                    ((float*)Cout)[(size_t)row * N + col] = vv;
                    Cbf[(size_t)row * N + col] = __float2bfloat16(vv);
                }
            }
        }
    }
}

// ---------------------------------------------------------------------------
// Mask scan: block covers 4096 int32 (16 KB); 4 nt int4 loads issued up front.
// ---------------------------------------------------------------------------
__global__ __launch_bounds__(256) void scan_kernel(
    const int* __restrict__ mask, int* __restrict__ counts,
    unsigned short* __restrict__ lists)
{
    const size_t base = (size_t)blockIdx.x * 4096 + (size_t)threadIdx.x * 4;
    i32x4 v[4];
#pragma unroll
    for (int k = 0; k < 4; ++k)
        v[k] = __builtin_nontemporal_load((const i32x4*)(mask + base + (size_t)k * 1024));

#pragma unroll
    for (int k = 0; k < 4; ++k) {
        if ((v[k].x | v[k].y | v[k].z | v[k].w) == 0) continue;
        const size_t e = base + (size_t)k * 1024;
        const int w  = (int)(e >> 15);
        const int t0 = (int)(e & (T_TOKENS - 1));
        if (v[k].x) { const int p = atomicAdd(&counts[t0+0], 1); if (p < CAP) lists[(size_t)(t0+0)*CAP+p] = (unsigned short)w; }
        if (v[k].y) { const int p = atomicAdd(&counts[t0+1], 1); if (p < CAP) lists[(size_t)(t0+1)*CAP+p] = (unsigned short)w; }
        if (v[k].z) { const int p = atomicAdd(&counts[t0+2], 1); if (p < CAP) lists[(size_t)(t0+2)*CAP+p] = (unsigned short)w; }
        if (v[k].w) { const int p = atomicAdd(&counts[t0+3], 1); if (p < CAP) lists[(size_t)(t0+3)*CAP+p] = (unsigned short)w; }
    }
}

// ---------------------------------------------------------------------------
// Per-token gather: x_new[t] = x[t] + sum_{w in list[t]} words_bf16[w].
// ---------------------------------------------------------------------------
__device__ inline void acc_bf8(f32x4& a, f32x4& b, bf16x8 r)
{
    a.x += __uint_as_float(((u32)(unsigned short)r[0]) << 16);
    a.y += __uint_as_float(((u32)(unsigned short)r[1]) << 16);
    a.z += __uint_as_float(((u32)(unsigned short)r[2]) << 16);
    a.w += __uint_as_float(((u32)(unsigned short)r[3]) << 16);
    b.x += __uint_as_float(((u32)(unsigned short)r[4]) << 16);
    b.y += __uint_as_float(((u32)(unsigned short)r[5]) << 16);
    b.z += __uint_as_float(((u32)(unsigned short)r[6]) << 16);
    b.w += __uint_as_float(((u32)(unsigned short)r[7]) << 16);
}

__global__ __launch_bounds__(256) void scatter_add_kernel(
    const float* __restrict__ x, const __hip_bfloat16* __restrict__ words_bf,
    const int* __restrict__ counts, const unsigned short* __restrict__ lists,
    float* __restrict__ x_new)
{
    const int t = __builtin_amdgcn_readfirstlane(
        (int)blockIdx.x * 4 + ((int)threadIdx.x >> 6));
    const int lane = threadIdx.x & 63;
    const size_t base = (size_t)t * N_EMBD + lane * 8;

    f32x4 s0a = __builtin_nontemporal_load((const f32x4*)(x + base));
    f32x4 s0b = __builtin_nontemporal_load((const f32x4*)(x + base + 4));
    f32x4 s1a = {0.f, 0.f, 0.f, 0.f};
    f32x4 s1b = {0.f, 0.f, 0.f, 0.f};

    const int cnt = min(counts[t], CAP);
    const unsigned short* lst = &lists[(size_t)t * CAP];

    int i = 0;
    for (; i + 2 <= cnt; i += 2) {
        const bf16x8 r0 = *(const bf16x8*)(words_bf + (size_t)lst[i]     * N_EMBD + lane * 8);
        const bf16x8 r1 = *(const bf16x8*)(words_bf + (size_t)lst[i + 1] * N_EMBD + lane * 8);
        acc_bf8(s0a, s0b, r0);
        acc_bf8(s1a, s1b, r1);
    }
    if (i < cnt) {
        const bf16x8 r0 = *(const bf16x8*)(words_bf + (size_t)lst[i] * N_EMBD + lane * 8);
        acc_bf8(s0a, s0b, r0);
    }
    s0a += s1a; s0b += s1b;
    __builtin_nontemporal_store(s0a, (f32x4*)(x_new + base));
    __builtin_nontemporal_store(s0b, (f32x4*)(x_new + base + 4));
}

// ---------------------------------------------------------------------------
extern "C" void kernel_launch(void* const* d_in, const int* in_sizes, int n_in,
                              void* d_out, int out_size, void* d_ws, size_t ws_size,
                              hipStream_t stream)
{
    const float* in_words = (const float*)d_in[0];
    const float* x        = (const float*)d_in[1];
    const int*   mask     = (const int*)d_in[2];   // numpy bool -> int32 per harness
    const float* W_fc     = (const float*)d_in[3];
    const float* W_proj   = (const float*)d_in[4];

    float* out_words = (float*)d_out;                        // [4096, 512]
    float* out_x     = out_words + (size_t)W_WORDS * N_EMBD; // [32768, 512]

    char* ws = (char*)d_ws;
    __hip_bfloat16* words_bf = (__hip_bfloat16*)(ws);                    //  4 MiB
    __hip_bfloat16* WfcT     = (__hip_bfloat16*)(ws + (4u << 20));       //  2 MiB [2048][512]
    __hip_bfloat16* WprojT   = (__hip_bfloat16*)(ws + (6u << 20));       //  2 MiB [512][2048]
    __hip_bfloat16* h_bf     = (__hip_bfloat16*)(ws + (8u << 20));       // 16 MiB [4096][2048]
    __hip_bfloat16* wout_bf  = (__hip_bfloat16*)(ws + (24u << 20));      //  4 MiB bf16 shadow
    int*            counts   = (int*)(ws + (28u << 20));                 // 128 KiB
    unsigned short* lists    = (unsigned short*)(ws + (28u << 20) + T_TOKENS * 4); // 4 MiB

    // Phase 0: prep (convert + transposes + zero counts)
    prep_kernel<<<3104, 256, 0, stream>>>(in_words, words_bf, W_fc, WfcT,
                                          W_proj, WprojT, counts);

    // Phase 1: GEMM1+GELU: h_bf = gelu(words_bf @ W_fc)  [4096, 2048]
    // 512 tiles = 32 Mblk x 16 Nblk, 512 thr, KSUB=4, XCD-chunked
    gemm_bf16_mfma_kernel<128, 128, 0, 4, 16, 512>
        <<<512, 512, 0, stream>>>(
            words_bf, WfcT, nullptr, h_bf, nullptr, W_WORDS, N_HIDDEN, N_EMBD);

    // Phase 2: GEMM2+residual: out_words (f32) + wout_bf (bf16 shadow)
    // 512 tiles = 64 Mblk x 8 Nblk, 512 thr, KSUB=4, XCD-chunked
    gemm_bf16_mfma_kernel<64, 64, 1, 4, 8, 512>
        <<<512, 512, 0, stream>>>(
            h_bf, WprojT, in_words, out_words, wout_bf, W_WORDS, N_EMBD, N_HIDDEN);

    // Phase 3: mask scan -> per-token word lists
    scan_kernel<<<32768, 256, 0, stream>>>(mask, counts, lists);

    // Phase 4: gather-accumulate into x_new (bf16 gathers)
    scatter_add_kernel<<<T_TOKENS / 4, 256, 0, stream>>>(
        x, wout_bf, counts, lists, out_x);
}